// Round 11
// baseline (518.674 us; speedup 1.0000x reference)
//
#include <hip/hip_runtime.h>

#define HIDDEN 32
#define FF 40
#define SEQ_T 512
#define RD 8     // ring depth; producer/consumer slot distance (disjoint mod 8)

typedef _Float16 half8 __attribute__((ext_vector_type(8)));
typedef __attribute__((ext_vector_type(4))) float float4v;
typedef __attribute__((ext_vector_type(4))) unsigned uint4v;
typedef __attribute__((ext_vector_type(2))) unsigned uint2v;

// ---------------------------------------------------------------------------
// R20 = R19 (role rotation spreading producers across SIMDs) MINUS setprio.
// R19's 1.6x regression was a priority-starvation mesh: spread producers at
// prio 1 starved co-SIMD consumers of OTHER blocks (prio 0), serializing
// producer+consumer per SIMD and coupling 4 blocks' barriers. VALU-work
// conservation (41%x454 == 68%x286) proves it was pure added stall.
// R17 accounting now closes: all 4 co-resident blocks' wave0-producers land
// on SIMD0 (wave->SIMD = wv mod 4), 4 x 3steps x ~320cy = 3840cy issue ~
// 4032cy measured phase -> SIMD0 is ~95% issue-busy (the clock); SIMDs 1-3
// are ~35% busy. Fix: spread producers via role = (wv - hash(bx)) & 3 with
// EQUAL priority -- fair round-robin gives each SIMD ~1 producer + ~3
// consumers (~2000cy issue/phase). Arithmetic bit-identical to R17.
// ---------------------------------------------------------------------------

__global__ __launch_bounds__(256, 1) void rnn_prep(
    const float* __restrict__ W1hh, const float* __restrict__ b1hh,
    const float* __restrict__ W2hh, const float* __restrict__ b2hh,
    const float* __restrict__ W1ho, const float* __restrict__ b1ho,
    unsigned short* __restrict__ acatP)
{
    const int idx = blockIdx.x * 256 + threadIdx.x;
    if (idx >= 96 * 64) return;
    const int mrow = idx >> 6, s = idx & 63;

    const bool hh = mrow < 48;
    const int col = hh ? mrow : mrow - 48;
    float val = 0.f;
    if (col < FF && s < 42) {
        const float* W1 = hh ? W1hh : W1ho;
        const float* b1 = hh ? b1hh : b1ho;
        if (s < FF) {                 // A[s, col] = (W2hh^T W1)[s, col]
            for (int i = 0; i < HIDDEN; ++i)
                val = __builtin_fmaf(W2hh[s * HIDDEN + i], W1[i * FF + col], val);
        } else if (s == 40) {         // u-channel weight
            val = W1[HIDDEN * FF + col];
        } else {                      // s == 41: folded bias channel
            val = b1[col];
            for (int i = 0; i < HIDDEN; ++i)
                val = __builtin_fmaf(b2hh[i], W1[i * FF + col], val);
        }
    }
    const _Float16 hv = (_Float16)val;   // RNE
    acatP[idx] = __builtin_bit_cast(unsigned short, hv);
}

__device__ __forceinline__ float sigmoid_fast(float x) {
    const float e = __builtin_amdgcn_exp2f(-x * 1.44269504088896341f);
    return __builtin_amdgcn_rcpf(1.0f + e);
}

// packed f32->f16 (RTZ), a lands in the LOW half
__device__ __forceinline__ unsigned cvt_pkrtz_u(float a, float b) {
    auto h = __builtin_amdgcn_cvt_pkrtz(a, b);   // __fp16 ext_vector(2)
    return __builtin_bit_cast(unsigned, h);
}

__global__ __launch_bounds__(256, 4) void rnn_main(
    const float* __restrict__ inputs,
    const unsigned short* __restrict__ acatP,
    const float* __restrict__ W1hh, const float* __restrict__ b1hh,
    const float* __restrict__ W1ho, const float* __restrict__ b1ho,
    const float* __restrict__ W2ho, const float* __restrict__ b2ho,
    float* __restrict__ ys)
{
    // 72-ushort rows (144 B): S[40] | u | 1.0 | pad[30]; bank span 4(r+g)%32
    __shared__ __align__(16) unsigned short ring[RD][16][72];   // 18432 B

    const int tid = threadIdx.x;
    const int wv  = __builtin_amdgcn_readfirstlane(tid >> 6);
    // role rotation: spread producer waves across SIMDs (wave wv -> SIMD wv%4;
    // co-resident blocks get different pw). EQUAL priority for all waves.
    const unsigned bx = blockIdx.x;
    const int pw = (int)((bx ^ (bx >> 2) ^ (bx >> 4) ^ (bx >> 6) ^ (bx >> 8)) & 3u);
    const int role = (wv - pw) & 3;   // 0 = hh producer, 1..3 = ho consumers
    const int l = tid & 63;
    const int r = l & 15;        // batch row within tile
    const int g = l >> 4;        // quad
    const size_t rowbase = (size_t)(blockIdx.x * 16 + r) * SEQ_T;
    const float* __restrict__ in_row = inputs + rowbase;

    // ---- zero the ring (pad slots 42..71 must read as 0 forever) ----
    {
        uint4v* zp = (uint4v*)&ring[0][0][0];
        const uint4v z4 = {0u, 0u, 0u, 0u};
#pragma unroll
        for (int i = 0; i < 5; ++i) {
            const int idx = tid + 256 * i;
            if (idx < 1152) zp[idx] = z4;    // 1152 * 16 B = 18432 B
        }
    }

    // ---- A-frags: producer hh m-tiles 0-2, consumers ho m-tiles 3-5 ----
    half8 A[3][2];
    const int mb = (role == 0) ? 0 : 3;
#pragma unroll
    for (int mt = 0; mt < 3; ++mt)
#pragma unroll
        for (int ks = 0; ks < 2; ++ks)
            A[mt][ks] = *(const half8*)(acatP + ((mb + mt) * 16 + r) * 64 + ks * 32 + g * 8);

    float w2o_l[3][4];
#pragma unroll
    for (int mt = 0; mt < 3; ++mt)
#pragma unroll
        for (int q = 0; q < 4; ++q) {
            const int j = 16 * mt + 4 * g + q;
            w2o_l[mt][q] = (j < FF) ? W2ho[j] : 0.f;
        }
    const float b2o = b2ho[0];
    const bool out16 = (l < 16);

    auto load_frags = [&](int sl, half8 (&f)[2]) {
        const unsigned short* p = &ring[sl][r][0];
        f[0] = *(const half8*)(p + g * 8);
        f[1] = *(const half8*)(p + 32 + g * 8);
    };

    // two independent 1-deep MFMA chains per m-tile + one vector add
    auto do_mfma = [&](const half8 (&f)[2], float4v (&acc)[3]) {
#pragma unroll
        for (int mt = 0; mt < 3; ++mt) {
            float4v a = (float4v)0.f, b = (float4v)0.f;
            a = __builtin_amdgcn_mfma_f32_16x16x32_f16(A[mt][0], f[0], a, 0, 0, 0);
            b = __builtin_amdgcn_mfma_f32_16x16x32_f16(A[mt][1], f[1], b, 0, 0, 0);
            acc[mt] = a + b;
        }
    };

    // sigmoid + fp16 pack + ring store: S halves 4j..4j+3 at dwords 2j,2j+1
    // (j = 4mt+g < 10); u/bias dword 20 written by the g==3 quad
    auto store_s = [&](int slot, const float4v (&z)[3], float u_next) {
        unsigned* bp = (unsigned*)&ring[slot][r][0];
#pragma unroll
        for (int mt = 0; mt < 3; ++mt) {
            const float s0 = sigmoid_fast(z[mt][0]);
            const float s1 = sigmoid_fast(z[mt][1]);
            const float s2 = sigmoid_fast(z[mt][2]);
            const float s3 = sigmoid_fast(z[mt][3]);
            const unsigned p01 = cvt_pkrtz_u(s0, s1);
            const unsigned p23 = cvt_pkrtz_u(s2, s3);
            const int j = 4 * mt + g;
            if (j < 10) {
                uint2v hp;
                hp.x = p01; hp.y = p23;
                *(uint2v*)(bp + 2 * j) = hp;
            }
        }
        if (g == 3) bp[20] = cvt_pkrtz_u(u_next, 1.0f);   // [1.0h : u] halves 40,41
    };

    __syncthreads();   // zeroing complete before prologue writes slot 0

    // ---- prologue: t = 0 ----
    float uc[3];
    if (role == 0) {
        const float u0 = in_row[0];
        float4v z[3];
#pragma unroll
        for (int mt = 0; mt < 3; ++mt)
#pragma unroll
            for (int q = 0; q < 4; ++q) {
                const int n = 16 * mt + 4 * g + q;
                const int nc = n < FF ? n : FF - 1;
                z[mt][q] = __builtin_fmaf(u0, W1hh[HIDDEN * FF + nc], b1hh[nc]);
            }
        store_s(0, z, in_row[1]);   // slot 0 = S(0) + u(1)
        uc[0] = in_row[2]; uc[1] = in_row[3]; uc[2] = in_row[4];
    } else if (role == 1) {
        const float u0 = in_row[0];
        float op = 0.f;
#pragma unroll
        for (int mt = 0; mt < 3; ++mt)
#pragma unroll
            for (int q = 0; q < 4; ++q) {
                const int n = 16 * mt + 4 * g + q;
                const int nc = n < FF ? n : FF - 1;
                const float so = sigmoid_fast(
                    __builtin_fmaf(u0, W1ho[HIDDEN * FF + nc], b1ho[nc]));
                op = __builtin_fmaf(so, w2o_l[mt][q], op);
            }
        op += __shfl_xor(op, 16);
        op += __shfl_xor(op, 32);
        if (out16) ys[rowbase] = op + b2o;
    }
    __syncthreads();

    // ---- phase loop: producer runs steps [3p+1..3p+3]; consumer role w
    // (1..3) runs the single step t = 3p-2+(w-1) ----
    for (int p = 0; p < 172; ++p) {
        if (role == 0) {
            const int tb = 3 * p + 1;
            float un[3];
#pragma unroll
            for (int i = 0; i < 3; ++i) {
                int tn = tb + 4 + i; tn = tn < SEQ_T ? tn : SEQ_T - 1;
                un[i] = in_row[tn];     // u for next phase
            }
#pragma unroll
            for (int i = 0; i < 3; ++i) {
                const int t = tb + i;
                if (t < SEQ_T) {
                    half8 f[2];
                    load_frags((t - 1) & (RD - 1), f);
                    float4v z[3];
                    do_mfma(f, z);
                    store_s(t & (RD - 1), z, uc[i]);
                }
            }
            uc[0] = un[0]; uc[1] = un[1]; uc[2] = un[2];
        } else {
            const int t = 3 * p - 2 + (role - 1);
            if (t >= 1 && t < SEQ_T) {
                half8 f[2];
                load_frags((t - 1) & (RD - 1), f);
                float4v acc[3];
                do_mfma(f, acc);
                float op = 0.f;
#pragma unroll
                for (int mt = 0; mt < 3; ++mt)
#pragma unroll
                    for (int q = 0; q < 4; ++q)
                        op = __builtin_fmaf(sigmoid_fast(acc[mt][q]),
                                            w2o_l[mt][q], op);
                op += __shfl_xor(op, 16);
                op += __shfl_xor(op, 32);
                if (out16) ys[rowbase + t] = op + b2o;
            }
        }
        __syncthreads();
    }
}

extern "C" void kernel_launch(void* const* d_in, const int* in_sizes, int n_in,
                              void* d_out, int out_size, void* d_ws, size_t ws_size,
                              hipStream_t stream) {
    const float* inputs = (const float*)d_in[0];
    const float* W1hh   = (const float*)d_in[1];
    const float* b1hh   = (const float*)d_in[2];
    const float* W2hh   = (const float*)d_in[3];
    const float* b2hh   = (const float*)d_in[4];
    const float* W1ho   = (const float*)d_in[5];
    const float* b1ho   = (const float*)d_in[6];
    const float* W2ho   = (const float*)d_in[7];
    const float* b2ho   = (const float*)d_in[8];
    float* ys = (float*)d_out;

    unsigned short* acatP = (unsigned short*)d_ws;    // 96*64 ushorts (fp16)

    const int B = in_sizes[0] / SEQ_T;   // 16384

    rnn_prep<<<(96 * 64 + 255) / 256, 256, 0, stream>>>(
        W1hh, b1hh, W2hh, b2hh, W1ho, b1ho, acatP);

    const int blocks = B / 16;           // 1024 blocks x 4 waves (1 hh + 3 ho)
    rnn_main<<<blocks, 256, 0, stream>>>(
        inputs, acatP, W1hh, b1hh, W1ho, b1ho, W2ho, b2ho, ys);
}

// Round 12
// 333.112 us; speedup vs baseline: 1.5571x; 1.5571x over previous
//
#include <hip/hip_runtime.h>

#define HIDDEN 32
#define FF 40
#define SEQ_T 512
#define RD 16    // ring depth; 6-step phases: writes {6p+1..6p+6}, reads {6p-6..6p-1} disjoint mod 16

typedef _Float16 half8 __attribute__((ext_vector_type(8)));
typedef __attribute__((ext_vector_type(4))) float float4v;
typedef __attribute__((ext_vector_type(4))) unsigned uint4v;
typedef __attribute__((ext_vector_type(2))) unsigned uint2v;

// ---------------------------------------------------------------------------
// R21 = R17 (best passing, 286us kernel: single-plane fp16 K=64, wave0 hh
// producer + waves1-3 ho consumers, setprio on producer) + producer-issue
// trims. R19/R20 proved role-placement manipulation is a dead axis (both
// regress 1.6x, with AND without setprio -> heterogeneous per-SIMD streams
// + cross-block barrier coupling de-phase into a convoy). R17's homogeneity
// (same-role waves share SIMDs, producers phase-lock each other) stays.
// Issue accounting: producer step ~337cy (192 trans + 145 VALU); 4 blocks x
// 3 steps x 337 = 4044 ~ 4032cy measured phase -> producer-SIMD issue IS the
// wall. Cuts: (1) merged MFMA chains (acc=mfma(A1,f1,mfma(A0,f0,0))):
// -12 v_add_f32 = -24cy/step, chain +35cy hidden by 4 interleaved producers;
// (2) 6-step phases @ RD=16 (36.9KB ring, 4 blocks/CU at 147KB): barriers
// 172->87. Arithmetic: fp32 reassociation only.
// ---------------------------------------------------------------------------

__global__ __launch_bounds__(256, 1) void rnn_prep(
    const float* __restrict__ W1hh, const float* __restrict__ b1hh,
    const float* __restrict__ W2hh, const float* __restrict__ b2hh,
    const float* __restrict__ W1ho, const float* __restrict__ b1ho,
    unsigned short* __restrict__ acatP)
{
    const int idx = blockIdx.x * 256 + threadIdx.x;
    if (idx >= 96 * 64) return;
    const int mrow = idx >> 6, s = idx & 63;

    const bool hh = mrow < 48;
    const int col = hh ? mrow : mrow - 48;
    float val = 0.f;
    if (col < FF && s < 42) {
        const float* W1 = hh ? W1hh : W1ho;
        const float* b1 = hh ? b1hh : b1ho;
        if (s < FF) {                 // A[s, col] = (W2hh^T W1)[s, col]
            for (int i = 0; i < HIDDEN; ++i)
                val = __builtin_fmaf(W2hh[s * HIDDEN + i], W1[i * FF + col], val);
        } else if (s == 40) {         // u-channel weight
            val = W1[HIDDEN * FF + col];
        } else {                      // s == 41: folded bias channel
            val = b1[col];
            for (int i = 0; i < HIDDEN; ++i)
                val = __builtin_fmaf(b2hh[i], W1[i * FF + col], val);
        }
    }
    const _Float16 hv = (_Float16)val;   // RNE
    acatP[idx] = __builtin_bit_cast(unsigned short, hv);
}

__device__ __forceinline__ float sigmoid_fast(float x) {
    const float e = __builtin_amdgcn_exp2f(-x * 1.44269504088896341f);
    return __builtin_amdgcn_rcpf(1.0f + e);
}

// packed f32->f16 (RTZ), a lands in the LOW half
__device__ __forceinline__ unsigned cvt_pkrtz_u(float a, float b) {
    auto h = __builtin_amdgcn_cvt_pkrtz(a, b);   // __fp16 ext_vector(2)
    return __builtin_bit_cast(unsigned, h);
}

__global__ __launch_bounds__(256, 4) void rnn_main(
    const float* __restrict__ inputs,
    const unsigned short* __restrict__ acatP,
    const float* __restrict__ W1hh, const float* __restrict__ b1hh,
    const float* __restrict__ W1ho, const float* __restrict__ b1ho,
    const float* __restrict__ W2ho, const float* __restrict__ b2ho,
    float* __restrict__ ys)
{
    // 72-ushort rows (144 B): S[40] | u | 1.0 | pad[30]; bank span 4(r+g)%32
    __shared__ __align__(16) unsigned short ring[RD][16][72];   // 36864 B

    const int tid = threadIdx.x;
    const int wv  = __builtin_amdgcn_readfirstlane(tid >> 6);  // 0=hh prod, 1..3=ho cons
    const int l = tid & 63;
    const int r = l & 15;        // batch row within tile
    const int g = l >> 4;        // quad
    const size_t rowbase = (size_t)(blockIdx.x * 16 + r) * SEQ_T;
    const float* __restrict__ in_row = inputs + rowbase;

    // producer wave gets issue priority (inert if co-SIMD waves are all
    // producers, helpful otherwise; R17-verbatim)
    if (wv == 0) __builtin_amdgcn_s_setprio(1);

    // ---- zero the ring (pad slots 42..71 must read as 0 forever) ----
    {
        uint4v* zp = (uint4v*)&ring[0][0][0];
        const uint4v z4 = {0u, 0u, 0u, 0u};
#pragma unroll
        for (int i = 0; i < 9; ++i)
            zp[tid + 256 * i] = z4;          // 2304 * 16 B = 36864 B exactly
    }

    // ---- A-frags: producer hh m-tiles 0-2, consumers ho m-tiles 3-5 ----
    half8 A[3][2];
    const int mb = (wv == 0) ? 0 : 3;
#pragma unroll
    for (int mt = 0; mt < 3; ++mt)
#pragma unroll
        for (int ks = 0; ks < 2; ++ks)
            A[mt][ks] = *(const half8*)(acatP + ((mb + mt) * 16 + r) * 64 + ks * 32 + g * 8);

    float w2o_l[3][4];
#pragma unroll
    for (int mt = 0; mt < 3; ++mt)
#pragma unroll
        for (int q = 0; q < 4; ++q) {
            const int j = 16 * mt + 4 * g + q;
            w2o_l[mt][q] = (j < FF) ? W2ho[j] : 0.f;
        }
    const float b2o = b2ho[0];
    const bool out16 = (l < 16);

    auto load_frags = [&](int sl, half8 (&f)[2]) {
        const unsigned short* p = &ring[sl][r][0];
        f[0] = *(const half8*)(p + g * 8);
        f[1] = *(const half8*)(p + 32 + g * 8);
    };

    // merged serial MFMA chain (saves the vector add; chain latency hidden
    // by co-resident producer waves)
    auto do_mfma = [&](const half8 (&f)[2], float4v (&acc)[3]) {
#pragma unroll
        for (int mt = 0; mt < 3; ++mt) {
            float4v a = (float4v)0.f;
            a = __builtin_amdgcn_mfma_f32_16x16x32_f16(A[mt][0], f[0], a, 0, 0, 0);
            a = __builtin_amdgcn_mfma_f32_16x16x32_f16(A[mt][1], f[1], a, 0, 0, 0);
            acc[mt] = a;
        }
    };

    // sigmoid + fp16 pack + ring store: S halves 4j..4j+3 at dwords 2j,2j+1
    // (j = 4mt+g < 10); u/bias dword 20 written by the g==3 quad
    auto store_s = [&](int slot, const float4v (&z)[3], float u_next) {
        unsigned* bp = (unsigned*)&ring[slot][r][0];
#pragma unroll
        for (int mt = 0; mt < 3; ++mt) {
            const float s0 = sigmoid_fast(z[mt][0]);
            const float s1 = sigmoid_fast(z[mt][1]);
            const float s2 = sigmoid_fast(z[mt][2]);
            const float s3 = sigmoid_fast(z[mt][3]);
            const unsigned p01 = cvt_pkrtz_u(s0, s1);
            const unsigned p23 = cvt_pkrtz_u(s2, s3);
            const int j = 4 * mt + g;
            if (j < 10) {
                uint2v hp;
                hp.x = p01; hp.y = p23;
                *(uint2v*)(bp + 2 * j) = hp;
            }
        }
        if (g == 3) bp[20] = cvt_pkrtz_u(u_next, 1.0f);   // [1.0h : u] halves 40,41
    };

    __syncthreads();   // zeroing complete before prologue writes slot 0

    // ---- prologue: t = 0 ----
    float uc[6];
    if (wv == 0) {
        const float u0 = in_row[0];
        float4v z[3];
#pragma unroll
        for (int mt = 0; mt < 3; ++mt)
#pragma unroll
            for (int q = 0; q < 4; ++q) {
                const int n = 16 * mt + 4 * g + q;
                const int nc = n < FF ? n : FF - 1;
                z[mt][q] = __builtin_fmaf(u0, W1hh[HIDDEN * FF + nc], b1hh[nc]);
            }
        store_s(0, z, in_row[1]);   // slot 0 = S(0) + u(1)
#pragma unroll
        for (int i = 0; i < 6; ++i) uc[i] = in_row[2 + i];  // u(t+1) for t=1..6
    } else if (wv == 1) {
        const float u0 = in_row[0];
        float op = 0.f;
#pragma unroll
        for (int mt = 0; mt < 3; ++mt)
#pragma unroll
            for (int q = 0; q < 4; ++q) {
                const int n = 16 * mt + 4 * g + q;
                const int nc = n < FF ? n : FF - 1;
                const float so = sigmoid_fast(
                    __builtin_fmaf(u0, W1ho[HIDDEN * FF + nc], b1ho[nc]));
                op = __builtin_fmaf(so, w2o_l[mt][q], op);
            }
        op += __shfl_xor(op, 16);
        op += __shfl_xor(op, 32);
        if (out16) ys[rowbase] = op + b2o;
    }
    __syncthreads();

    // ---- phase loop (87 phases x 6 steps): producer runs t=6p+1..6p+6;
    // consumer wave w (1..3) runs t = 6p-5+(w-1)+3i, i=0,1 ----
    for (int p = 0; p < 87; ++p) {
        if (wv == 0) {
            const int tb = 6 * p + 1;
            float un[6];
#pragma unroll
            for (int i = 0; i < 6; ++i) {
                int tn = tb + 7 + i;            // u((6(p+1)+1+i)+1) = in_row[6p+8+i]
                tn = tn < SEQ_T ? tn : SEQ_T - 1;
                un[i] = in_row[tn];
            }
#pragma unroll
            for (int i = 0; i < 6; ++i) {
                const int t = tb + i;
                if (t < SEQ_T) {
                    half8 f[2];
                    load_frags((t - 1) & (RD - 1), f);
                    float4v z[3];
                    do_mfma(f, z);
                    store_s(t & (RD - 1), z, uc[i]);
                }
            }
#pragma unroll
            for (int i = 0; i < 6; ++i) uc[i] = un[i];
        } else {
#pragma unroll
            for (int i = 0; i < 2; ++i) {
                const int t = 6 * p - 5 + (wv - 1) + 3 * i;
                if (t >= 1 && t < SEQ_T) {
                    half8 f[2];
                    load_frags((t - 1) & (RD - 1), f);
                    float4v acc[3];
                    do_mfma(f, acc);
                    float op = 0.f;
#pragma unroll
                    for (int mt = 0; mt < 3; ++mt)
#pragma unroll
                        for (int q = 0; q < 4; ++q)
                            op = __builtin_fmaf(sigmoid_fast(acc[mt][q]),
                                                w2o_l[mt][q], op);
                    op += __shfl_xor(op, 16);
                    op += __shfl_xor(op, 32);
                    if (out16) ys[rowbase + t] = op + b2o;
                }
            }
        }
        __syncthreads();
    }
}

extern "C" void kernel_launch(void* const* d_in, const int* in_sizes, int n_in,
                              void* d_out, int out_size, void* d_ws, size_t ws_size,
                              hipStream_t stream) {
    const float* inputs = (const float*)d_in[0];
    const float* W1hh   = (const float*)d_in[1];
    const float* b1hh   = (const float*)d_in[2];
    const float* W2hh   = (const float*)d_in[3];
    const float* b2hh   = (const float*)d_in[4];
    const float* W1ho   = (const float*)d_in[5];
    const float* b1ho   = (const float*)d_in[6];
    const float* W2ho   = (const float*)d_in[7];
    const float* b2ho   = (const float*)d_in[8];
    float* ys = (float*)d_out;

    unsigned short* acatP = (unsigned short*)d_ws;    // 96*64 ushorts (fp16)

    const int B = in_sizes[0] / SEQ_T;   // 16384

    rnn_prep<<<(96 * 64 + 255) / 256, 256, 0, stream>>>(
        W1hh, b1hh, W2hh, b2hh, W1ho, b1ho, acatP);

    const int blocks = B / 16;           // 1024 blocks x 4 waves (1 hh + 3 ho)
    rnn_main<<<blocks, 256, 0, stream>>>(
        inputs, acatP, W1hh, b1hh, W1ho, b1ho, W2ho, b2ho, ys);
}